// Round 1
// baseline (3944.915 us; speedup 1.0000x reference)
//
#include <hip/hip_runtime.h>
#include <math.h>

#define B_ 32
#define L_ 336
#define C_ 321
#define P_ 96
#define E_ 4
#define H_ 2048
#define BC_ (B_*C_)          // 10272
#define INVc 0.99999500003749969f   // 1/sqrt(1+1e-5)

__device__ __forceinline__ float gelu_f(float x) {
    return 0.5f * x * (1.0f + erff(x * 0.70710678118654752440f));
}

// ---------------- zero out ----------------
__global__ void k_zero(float* __restrict__ p, int n) {
    int i = blockIdx.x * blockDim.x + threadIdx.x;
    if (i < n) p[i] = 0.f;
}

// ---------------- BN1 + transpose + pyramid pooling ----------------
// x: (B,L,C) -> h: (BC,336) token-major, plus s2 (168), s1 (84), s0 (42)
__global__ __launch_bounds__(128) void k_bnpool(
    const float* __restrict__ x, const float* __restrict__ bw, const float* __restrict__ bb,
    float* __restrict__ h, float* __restrict__ s0, float* __restrict__ s1, float* __restrict__ s2)
{
    __shared__ float sh[336];
    __shared__ float sh2[168];
    __shared__ float sh1[84];
    int token = blockIdx.x;
    int b = token / C_, c = token % C_;
    int tid = threadIdx.x;
    const float* xb = x + (size_t)b * L_ * C_ + c;
    for (int l = tid; l < L_; l += 128) {
        float v = xb[(size_t)l * C_];
        v = v * (bw[c * L_ + l] * INVc) + bb[c * L_ + l];
        sh[l] = v;
        h[(size_t)token * L_ + l] = v;
    }
    __syncthreads();
    for (int i = tid; i < 168; i += 128) { float v = 0.5f * (sh[2*i] + sh[2*i+1]); sh2[i] = v; s2[(size_t)token*168 + i] = v; }
    __syncthreads();
    for (int i = tid; i < 84; i += 128) { float v = 0.5f * (sh2[2*i] + sh2[2*i+1]); sh1[i] = v; s1[(size_t)token*84 + i] = v; }
    __syncthreads();
    for (int i = tid; i < 42; i += 128) { float v = 0.5f * (sh1[2*i] + sh1[2*i+1]); s0[(size_t)token*42 + i] = v; }
}

// ---------------- generic guarded GEMM: D = [gelu](A@W^T + bias) [+ S] ----------------
// A:(M,K) W:(N,K) bias:(N) S:(M,N) D:(M,N).  BM=BN=64, BK=16, 256 thr, 4x4 micro.
template<int GELU, int ADD>
__global__ __launch_bounds__(256) void gemm_kernel(
    const float* __restrict__ A, const float* __restrict__ W,
    const float* __restrict__ bias, const float* __restrict__ S,
    float* __restrict__ D, int M, int N, int K)
{
    __shared__ __align__(16) float As[16][68];
    __shared__ __align__(16) float Ws[16][68];
    int m0 = blockIdx.x * 64, n0 = blockIdx.y * 64;
    int tid = threadIdx.x;
    int tr = tid >> 4, tc = tid & 15;
    float acc[4][4];
    #pragma unroll
    for (int i = 0; i < 4; ++i)
        #pragma unroll
        for (int j = 0; j < 4; ++j) acc[i][j] = 0.f;

    int nk = (K + 15) >> 4;
    for (int kt = 0; kt < nk; ++kt) {
        int k0 = kt * 16;
        #pragma unroll
        for (int it = 0; it < 4; ++it) {
            int elem = tid + it * 256;
            int row = elem >> 4, kk = elem & 15;
            int gm = m0 + row, gk = k0 + kk;
            As[kk][row] = (gm < M && gk < K) ? A[(size_t)gm * K + gk] : 0.f;
            int gn = n0 + row;
            Ws[kk][row] = (gn < N && gk < K) ? W[(size_t)gn * K + gk] : 0.f;
        }
        __syncthreads();
        #pragma unroll
        for (int kk = 0; kk < 16; ++kk) {
            float4 a4 = *reinterpret_cast<const float4*>(&As[kk][tr * 4]);
            float4 w4 = *reinterpret_cast<const float4*>(&Ws[kk][tc * 4]);
            float av[4] = {a4.x, a4.y, a4.z, a4.w};
            float wv[4] = {w4.x, w4.y, w4.z, w4.w};
            #pragma unroll
            for (int i = 0; i < 4; ++i)
                #pragma unroll
                for (int j = 0; j < 4; ++j) acc[i][j] += av[i] * wv[j];
        }
        __syncthreads();
    }
    #pragma unroll
    for (int i = 0; i < 4; ++i) {
        int m = m0 + tr * 4 + i;
        if (m >= M) continue;
        #pragma unroll
        for (int j = 0; j < 4; ++j) {
            int n = n0 + tc * 4 + j;
            if (n >= N) continue;
            float v = acc[i][j] + bias[n];
            if (GELU) v = gelu_f(v);
            if (ADD) v += S[(size_t)m * N + n];
            D[(size_t)m * N + n] = v;
        }
    }
}

// ---------------- BN2 elementwise ----------------
__global__ void k_bn2(const float* __restrict__ te, const float* __restrict__ w,
                      const float* __restrict__ bb, float* __restrict__ d)
{
    int idx = blockIdx.x * blockDim.x + threadIdx.x;
    if (idx >= BC_ * L_) return;
    int token = idx / L_;
    int l = idx - token * L_;
    int c = token % C_;
    d[idx] = te[idx] * (w[c * L_ + l] * INVc) + bb[c * L_ + l];
}

// ---------------- DDI sequential patch scan (token-parallel) ----------------
__global__ __launch_bounds__(256) void k_ddi(
    const float* __restrict__ d, const float* __restrict__ n1w, const float* __restrict__ n1b,
    const float* __restrict__ aggw, const float* __restrict__ aggb, float* __restrict__ ddi)
{
    __shared__ float sAw[144];
    __shared__ float sAb[12];
    int tid = threadIdx.x;
    if (tid < 144) sAw[tid] = aggw[tid];
    if (tid < 12) sAb[tid] = aggb[tid];
    __syncthreads();
    int token = blockIdx.x * blockDim.x + tid;
    if (token >= BC_) return;
    int c = token % C_;
    float w[12], bb[12], prev[12];
    #pragma unroll
    for (int p = 0; p < 12; ++p) { w[p] = n1w[c * 12 + p] * INVc; bb[p] = n1b[c * 12 + p]; }
    const float* drow = d + (size_t)token * L_;
    float* orow = ddi + (size_t)token * L_;
    #pragma unroll
    for (int p = 0; p < 12; ++p) { prev[p] = drow[p]; orow[p] = prev[p]; }
    for (int t = 0; t < 27; ++t) {
        float inp[12];
        #pragma unroll
        for (int p = 0; p < 12; ++p) inp[p] = prev[p] * w[p] + bb[p];
        float o[12];
        #pragma unroll
        for (int i = 0; i < 12; ++i) {
            float a = sAb[i];
            #pragma unroll
            for (int p = 0; p < 12; ++p) a += inp[p] * sAw[i * 12 + p];
            o[i] = gelu_f(a);
        }
        const float* xp = drow + 12 + t * 12;
        #pragma unroll
        for (int p = 0; p < 12; ++p) {
            float v = o[p] + xp[p];
            prev[p] = v;
            orow[12 + t * 12 + p] = v;
        }
    }
}

// ---------------- gating ----------------
__global__ void k_gate(const float* __restrict__ te, const float* __restrict__ gw,
                       const float* __restrict__ gb, float* __restrict__ gates)
{
    int token = blockIdx.x * blockDim.x + threadIdx.x;
    if (token >= BC_) return;
    const float* row = te + (size_t)token * L_;
    float acc[4] = {gb[0], gb[1], gb[2], gb[3]};
    for (int l = 0; l < L_; ++l) {
        float tv = row[l];
        #pragma unroll
        for (int e = 0; e < 4; ++e) acc[e] += tv * gw[e * L_ + l];
    }
    int im = 0;
    #pragma unroll
    for (int e = 1; e < 4; ++e) if (acc[e] > acc[im]) im = e;
    float second = -1e30f;
    #pragma unroll
    for (int e = 0; e < 4; ++e) if (e != im) second = fmaxf(second, acc[e]);
    float mx = acc[im];
    float s[4]; float ssum = 0.f;
    #pragma unroll
    for (int e = 0; e < 4; ++e) { s[e] = expf(acc[e] - mx); ssum += s[e]; }
    float dec[4]; float dmx = -1e30f;
    #pragma unroll
    for (int e = 0; e < 4; ++e) {
        s[e] /= ssum;
        dec[e] = (acc[e] < second) ? 10.f * logf(s[e] + 1.f) : 10.f * (expf(s[e]) - 1.f);
        dmx = fmaxf(dmx, dec[e]);
    }
    float g[4]; float gsum = 0.f;
    #pragma unroll
    for (int e = 0; e < 4; ++e) { g[e] = expf(dec[e] - dmx); gsum += g[e]; }
    #pragma unroll
    for (int e = 0; e < 4; ++e) gates[token * 4 + e] = g[e] / gsum;
}

// ---------------- fused expert MLP ----------------
// grid (BC/32, E). Block: 32 tokens, 1 expert, all H; eo kept in regs; atomicAdd across experts.
__global__ __launch_bounds__(256) void k_expert(
    const float* __restrict__ ddi, const float* __restrict__ gates,
    const float* __restrict__ ew1, const float* __restrict__ eb1,
    const float* __restrict__ ew2, const float* __restrict__ eb2,
    float* __restrict__ out)
{
    const int e = blockIdx.y;
    const int t0 = blockIdx.x * 32;
    const int tid = threadIdx.x;

    __shared__ __align__(16) float As[16][36];    // [k][token]
    __shared__ __align__(16) float Ws[16][68];    // [k][h]
    __shared__ __align__(16) float hidT[32][68];  // [token][h]

    const int th = tid & 15;   // h quad (GEMM1)
    const int tg = tid >> 4;   // token pair
    // GEMM2 reuses same decomposition: p group = th, token pair = tg

    float eo[2][6];
    #pragma unroll
    for (int j = 0; j < 2; ++j)
        #pragma unroll
        for (int i = 0; i < 6; ++i) eo[j][i] = 0.f;

    for (int htile = 0; htile < 32; ++htile) {
        const int hb = htile * 64;
        float acc[2][4];
        #pragma unroll
        for (int i = 0; i < 4; ++i) {
            float bv = eb1[e * H_ + hb + th * 4 + i];
            acc[0][i] = bv; acc[1][i] = bv;
        }
        for (int kt = 0; kt < 21; ++kt) {   // 336 = 21*16 exactly
            const int k0 = kt * 16;
            #pragma unroll
            for (int it = 0; it < 2; ++it) {
                int elem = tid + it * 256;
                int tok = elem >> 4, kk = elem & 15;
                As[kk][tok] = ddi[(size_t)(t0 + tok) * L_ + k0 + kk];
            }
            #pragma unroll
            for (int it = 0; it < 4; ++it) {
                int elem = tid + it * 256;
                int hh = elem >> 4, kk = elem & 15;
                Ws[kk][hh] = ew1[(size_t)(e * H_ + hb + hh) * L_ + k0 + kk];
            }
            __syncthreads();
            #pragma unroll
            for (int kk = 0; kk < 16; ++kk) {
                float4 w4 = *reinterpret_cast<const float4*>(&Ws[kk][th * 4]);
                float a0 = As[kk][tg * 2];
                float a1 = As[kk][tg * 2 + 1];
                acc[0][0] += a0 * w4.x; acc[0][1] += a0 * w4.y; acc[0][2] += a0 * w4.z; acc[0][3] += a0 * w4.w;
                acc[1][0] += a1 * w4.x; acc[1][1] += a1 * w4.y; acc[1][2] += a1 * w4.z; acc[1][3] += a1 * w4.w;
            }
            __syncthreads();
        }
        #pragma unroll
        for (int j = 0; j < 2; ++j) {
            float4 gv = make_float4(gelu_f(acc[j][0]), gelu_f(acc[j][1]), gelu_f(acc[j][2]), gelu_f(acc[j][3]));
            *reinterpret_cast<float4*>(&hidT[tg * 2 + j][th * 4]) = gv;
        }
        __syncthreads();
        for (int hh = 0; hh < 64; hh += 4) {
            float4 h0 = *reinterpret_cast<const float4*>(&hidT[tg * 2][hh]);
            float4 h1 = *reinterpret_cast<const float4*>(&hidT[tg * 2 + 1][hh]);
            #pragma unroll
            for (int i = 0; i < 6; ++i) {
                const float4 wv = *reinterpret_cast<const float4*>(&ew2[(size_t)(e * P_ + th * 6 + i) * H_ + hb + hh]);
                eo[0][i] += h0.x * wv.x + h0.y * wv.y + h0.z * wv.z + h0.w * wv.w;
                eo[1][i] += h1.x * wv.x + h1.y * wv.y + h1.z * wv.z + h1.w * wv.w;
            }
        }
        __syncthreads();
    }
    #pragma unroll
    for (int j = 0; j < 2; ++j) {
        int token = t0 + tg * 2 + j;
        float g = gates[token * 4 + e];
        int b = token / C_, c = token % C_;
        #pragma unroll
        for (int i = 0; i < 6; ++i) {
            int p = th * 6 + i;
            float v = g * (eo[j][i] + eb2[e * P_ + p]);
            atomicAdd(&out[(size_t)b * P_ * C_ + (size_t)p * C_ + c], v);
        }
    }
}

// ---------------- launch ----------------
extern "C" void kernel_launch(void* const* d_in, const int* in_sizes, int n_in,
                              void* d_out, int out_size, void* d_ws, size_t ws_size,
                              hipStream_t stream) {
    const float* x       = (const float*)d_in[0];
    const float* mdm_w   = (const float*)d_in[2];
    const float* mdm_b   = (const float*)d_in[3];
    const float* m0w1    = (const float*)d_in[4];
    const float* m0b1    = (const float*)d_in[5];
    const float* m0w2    = (const float*)d_in[6];
    const float* m0b2    = (const float*)d_in[7];
    const float* m1w1    = (const float*)d_in[8];
    const float* m1b1    = (const float*)d_in[9];
    const float* m1w2    = (const float*)d_in[10];
    const float* m1b2    = (const float*)d_in[11];
    const float* m2w1    = (const float*)d_in[12];
    const float* m2b1    = (const float*)d_in[13];
    const float* m2w2    = (const float*)d_in[14];
    const float* m2b2    = (const float*)d_in[15];
    const float* dbn_w   = (const float*)d_in[16];
    const float* dbn_b   = (const float*)d_in[17];
    const float* n1w     = (const float*)d_in[18];
    const float* n1b     = (const float*)d_in[19];
    const float* agg_w   = (const float*)d_in[20];
    const float* agg_b   = (const float*)d_in[21];
    const float* gate_w  = (const float*)d_in[22];
    const float* gate_b  = (const float*)d_in[23];
    const float* ew1     = (const float*)d_in[24];
    const float* eb1     = (const float*)d_in[25];
    const float* ew2     = (const float*)d_in[26];
    const float* eb2     = (const float*)d_in[27];
    float* out = (float*)d_out;

    float* ws   = (float*)d_ws;
    float* h    = ws;                        // BC*336, becomes te in-place
    float* s0   = h    + (size_t)BC_ * 336;  // BC*42
    float* s1   = s0   + (size_t)BC_ * 42;   // BC*84, becomes cur1 in-place
    float* s2   = s1   + (size_t)BC_ * 84;   // BC*168, becomes cur2 in-place
    float* gbuf = s2   + (size_t)BC_ * 168;  // BC*168 scratch
    float* dbuf = gbuf + (size_t)BC_ * 168;  // BC*336
    float* ddi  = dbuf + (size_t)BC_ * 336;  // BC*336
    float* gates= ddi  + (size_t)BC_ * 336;  // BC*4

    const int OUTN = B_ * P_ * C_;
    k_zero<<<(OUTN + 255) / 256, 256, 0, stream>>>(out, OUTN);
    k_bnpool<<<BC_, 128, 0, stream>>>(x, mdm_w, mdm_b, h, s0, s1, s2);

    // mixer stage 0: d=42 -> 84
    gemm_kernel<1,0><<<dim3(161,1), 256, 0, stream>>>(s0,   m0w1, m0b1, nullptr, gbuf, BC_, 42,  42);
    gemm_kernel<0,1><<<dim3(161,2), 256, 0, stream>>>(gbuf, m0w2, m0b2, s1,      s1,   BC_, 84,  42);
    // stage 1: 84 -> 168
    gemm_kernel<1,0><<<dim3(161,2), 256, 0, stream>>>(s1,   m1w1, m1b1, nullptr, gbuf, BC_, 84,  84);
    gemm_kernel<0,1><<<dim3(161,3), 256, 0, stream>>>(gbuf, m1w2, m1b2, s2,      s2,   BC_, 168, 84);
    // stage 2: 168 -> 336 (te := h in-place)
    gemm_kernel<1,0><<<dim3(161,3), 256, 0, stream>>>(s2,   m2w1, m2b1, nullptr, gbuf, BC_, 168, 168);
    gemm_kernel<0,1><<<dim3(161,6), 256, 0, stream>>>(gbuf, m2w2, m2b2, h,       h,    BC_, 336, 168);

    k_bn2<<<(BC_ * L_ + 255) / 256, 256, 0, stream>>>(h, dbn_w, dbn_b, dbuf);
    k_ddi<<<(BC_ + 255) / 256, 256, 0, stream>>>(dbuf, n1w, n1b, agg_w, agg_b, ddi);
    k_gate<<<(BC_ + 255) / 256, 256, 0, stream>>>(h, gate_w, gate_b, gates);
    k_expert<<<dim3(BC_ / 32, E_), 256, 0, stream>>>(ddi, gates, ew1, eb1, ew2, eb2, out);
}

// Round 2
// 994.051 us; speedup vs baseline: 3.9685x; 3.9685x over previous
//
#include <hip/hip_runtime.h>
#include <math.h>

#define B_ 32
#define L_ 336
#define C_ 321
#define P_ 96
#define E_ 4
#define H_ 2048
#define BC_ (B_*C_)          // 10272
#define KP1 352              // K1 padded to multiple of 32
#define INVc 0.99999500003749969f   // 1/sqrt(1+1e-5)

typedef __attribute__((ext_vector_type(8))) short short8v;
typedef __attribute__((ext_vector_type(4))) float f32x4;

__device__ __forceinline__ float gelu_f(float x) {
    return 0.5f * x * (1.0f + erff(x * 0.70710678118654752440f));
}

__device__ __forceinline__ unsigned rne16(float v) {
    unsigned u = __float_as_uint(v);
    return (u + 0x7fffu + ((u >> 16) & 1u)) >> 16;
}

// ---------------- zero out ----------------
__global__ void k_zero(float* __restrict__ p, int n) {
    int i = blockIdx.x * blockDim.x + threadIdx.x;
    if (i < n) p[i] = 0.f;
}

// ---------------- BN1 + transpose + pyramid pooling ----------------
__global__ __launch_bounds__(128) void k_bnpool(
    const float* __restrict__ x, const float* __restrict__ bw, const float* __restrict__ bb,
    float* __restrict__ h, float* __restrict__ s0, float* __restrict__ s1, float* __restrict__ s2)
{
    __shared__ float sh[336];
    __shared__ float sh2[168];
    __shared__ float sh1[84];
    int token = blockIdx.x;
    int b = token / C_, c = token % C_;
    int tid = threadIdx.x;
    const float* xb = x + (size_t)b * L_ * C_ + c;
    for (int l = tid; l < L_; l += 128) {
        float v = xb[(size_t)l * C_];
        v = v * (bw[c * L_ + l] * INVc) + bb[c * L_ + l];
        sh[l] = v;
        h[(size_t)token * L_ + l] = v;
    }
    __syncthreads();
    for (int i = tid; i < 168; i += 128) { float v = 0.5f * (sh[2*i] + sh[2*i+1]); sh2[i] = v; s2[(size_t)token*168 + i] = v; }
    __syncthreads();
    for (int i = tid; i < 84; i += 128) { float v = 0.5f * (sh2[2*i] + sh2[2*i+1]); sh1[i] = v; s1[(size_t)token*84 + i] = v; }
    __syncthreads();
    for (int i = tid; i < 42; i += 128) { float v = 0.5f * (sh1[2*i] + sh1[2*i+1]); s0[(size_t)token*42 + i] = v; }
}

// ---------------- generic guarded GEMM (mixer) ----------------
template<int GELU, int ADD>
__global__ __launch_bounds__(256) void gemm_kernel(
    const float* __restrict__ A, const float* __restrict__ W,
    const float* __restrict__ bias, const float* __restrict__ S,
    float* __restrict__ D, int M, int N, int K)
{
    __shared__ __align__(16) float As[16][68];
    __shared__ __align__(16) float Ws[16][68];
    int m0 = blockIdx.x * 64, n0 = blockIdx.y * 64;
    int tid = threadIdx.x;
    int tr = tid >> 4, tc = tid & 15;
    float acc[4][4];
    #pragma unroll
    for (int i = 0; i < 4; ++i)
        #pragma unroll
        for (int j = 0; j < 4; ++j) acc[i][j] = 0.f;

    int nk = (K + 15) >> 4;
    for (int kt = 0; kt < nk; ++kt) {
        int k0 = kt * 16;
        #pragma unroll
        for (int it = 0; it < 4; ++it) {
            int elem = tid + it * 256;
            int row = elem >> 4, kk = elem & 15;
            int gm = m0 + row, gk = k0 + kk;
            As[kk][row] = (gm < M && gk < K) ? A[(size_t)gm * K + gk] : 0.f;
            int gn = n0 + row;
            Ws[kk][row] = (gn < N && gk < K) ? W[(size_t)gn * K + gk] : 0.f;
        }
        __syncthreads();
        #pragma unroll
        for (int kk = 0; kk < 16; ++kk) {
            float4 a4 = *reinterpret_cast<const float4*>(&As[kk][tr * 4]);
            float4 w4 = *reinterpret_cast<const float4*>(&Ws[kk][tc * 4]);
            float av[4] = {a4.x, a4.y, a4.z, a4.w};
            float wv[4] = {w4.x, w4.y, w4.z, w4.w};
            #pragma unroll
            for (int i = 0; i < 4; ++i)
                #pragma unroll
                for (int j = 0; j < 4; ++j) acc[i][j] += av[i] * wv[j];
        }
        __syncthreads();
    }
    #pragma unroll
    for (int i = 0; i < 4; ++i) {
        int m = m0 + tr * 4 + i;
        if (m >= M) continue;
        #pragma unroll
        for (int j = 0; j < 4; ++j) {
            int n = n0 + tc * 4 + j;
            if (n >= N) continue;
            float v = acc[i][j] + bias[n];
            if (GELU) v = gelu_f(v);
            if (ADD) v += S[(size_t)m * N + n];
            D[(size_t)m * N + n] = v;
        }
    }
}

// ---------------- BN2 elementwise ----------------
__global__ void k_bn2(const float* __restrict__ te, const float* __restrict__ w,
                      const float* __restrict__ bb, float* __restrict__ d)
{
    int idx = blockIdx.x * blockDim.x + threadIdx.x;
    if (idx >= BC_ * L_) return;
    int token = idx / L_;
    int l = idx - token * L_;
    int c = token % C_;
    d[idx] = te[idx] * (w[c * L_ + l] * INVc) + bb[c * L_ + l];
}

// ---------------- DDI scan -> writes bf16 hi/lo planes (padded to 352) ----------------
__global__ __launch_bounds__(256) void k_ddi(
    const float* __restrict__ d, const float* __restrict__ n1w, const float* __restrict__ n1b,
    const float* __restrict__ aggw, const float* __restrict__ aggb,
    ushort* __restrict__ ahi, ushort* __restrict__ alo)
{
    __shared__ float sAw[144];
    __shared__ float sAb[12];
    int tid = threadIdx.x;
    if (tid < 144) sAw[tid] = aggw[tid];
    if (tid < 12) sAb[tid] = aggb[tid];
    __syncthreads();
    int token = blockIdx.x * blockDim.x + tid;
    if (token >= BC_) return;
    int c = token % C_;
    float w[12], bb[12], prev[12];
    #pragma unroll
    for (int p = 0; p < 12; ++p) { w[p] = n1w[c * 12 + p] * INVc; bb[p] = n1b[c * 12 + p]; }
    const float* drow = d + (size_t)token * L_;
    unsigned* hrow = (unsigned*)(ahi + (size_t)token * KP1);
    unsigned* lrow = (unsigned*)(alo + (size_t)token * KP1);

    auto store12 = [&](int base, const float* v) {
        #pragma unroll
        for (int j = 0; j < 6; ++j) {
            unsigned h0 = rne16(v[2*j]), h1 = rne16(v[2*j+1]);
            float f0 = __uint_as_float(h0 << 16), f1 = __uint_as_float(h1 << 16);
            unsigned l0 = rne16(v[2*j] - f0), l1 = rne16(v[2*j+1] - f1);
            hrow[(base >> 1) + j] = h0 | (h1 << 16);
            lrow[(base >> 1) + j] = l0 | (l1 << 16);
        }
    };

    #pragma unroll
    for (int p = 0; p < 12; ++p) prev[p] = drow[p];
    store12(0, prev);
    for (int t = 0; t < 27; ++t) {
        float inp[12];
        #pragma unroll
        for (int p = 0; p < 12; ++p) inp[p] = prev[p] * w[p] + bb[p];
        float o[12];
        #pragma unroll
        for (int i = 0; i < 12; ++i) {
            float a = sAb[i];
            #pragma unroll
            for (int p = 0; p < 12; ++p) a += inp[p] * sAw[i * 12 + p];
            o[i] = gelu_f(a);
        }
        const float* xp = drow + 12 + t * 12;
        #pragma unroll
        for (int p = 0; p < 12; ++p) prev[p] = o[p] + xp[p];
        store12(12 + t * 12, prev);
    }
    // pad 336..351 with zeros
    #pragma unroll
    for (int j = 0; j < 8; ++j) { hrow[168 + j] = 0u; lrow[168 + j] = 0u; }
}

// ---------------- gating ----------------
__global__ void k_gate(const float* __restrict__ te, const float* __restrict__ gw,
                       const float* __restrict__ gb, float* __restrict__ gates)
{
    int token = blockIdx.x * blockDim.x + threadIdx.x;
    if (token >= BC_) return;
    const float* row = te + (size_t)token * L_;
    float acc[4] = {gb[0], gb[1], gb[2], gb[3]};
    for (int l = 0; l < L_; ++l) {
        float tv = row[l];
        #pragma unroll
        for (int e = 0; e < 4; ++e) acc[e] += tv * gw[e * L_ + l];
    }
    int im = 0;
    #pragma unroll
    for (int e = 1; e < 4; ++e) if (acc[e] > acc[im]) im = e;
    float second = -1e30f;
    #pragma unroll
    for (int e = 0; e < 4; ++e) if (e != im) second = fmaxf(second, acc[e]);
    float mx = acc[im];
    float s[4]; float ssum = 0.f;
    #pragma unroll
    for (int e = 0; e < 4; ++e) { s[e] = expf(acc[e] - mx); ssum += s[e]; }
    float dec[4]; float dmx = -1e30f;
    #pragma unroll
    for (int e = 0; e < 4; ++e) {
        s[e] /= ssum;
        dec[e] = (acc[e] < second) ? 10.f * logf(s[e] + 1.f) : 10.f * (expf(s[e]) - 1.f);
        dmx = fmaxf(dmx, dec[e]);
    }
    float g[4]; float gsum = 0.f;
    #pragma unroll
    for (int e = 0; e < 4; ++e) { g[e] = expf(dec[e] - dmx); gsum += g[e]; }
    #pragma unroll
    for (int e = 0; e < 4; ++e) gates[token * 4 + e] = g[e] / gsum;
}

// ---------------- split fp32 -> bf16 hi/lo planes (K padded to Kp) ----------------
__global__ void k_split(const float* __restrict__ src, ushort* __restrict__ hi,
                        ushort* __restrict__ lo, int rows, int K, int Kp)
{
    int idx = blockIdx.x * blockDim.x + threadIdx.x;
    if (idx >= rows * Kp) return;
    int r = idx / Kp, k = idx - r * Kp;
    float v = (k < K) ? src[(size_t)r * K + k] : 0.f;
    unsigned h = rne16(v);
    float hf = __uint_as_float(h << 16);
    unsigned l = rne16(v - hf);
    hi[idx] = (ushort)h;
    lo[idx] = (ushort)l;
}

// ---------------- fused expert MLP via bf16x3 MFMA ----------------
// grid (161, 4). Block: 64 tokens x 1 expert, 4 waves = 2 token-groups x 2 h-halves.
__global__ __launch_bounds__(256, 3) void k_expert_mfma(
    const ushort* __restrict__ ahi, const ushort* __restrict__ alo,
    const ushort* __restrict__ w1hi, const ushort* __restrict__ w1lo,
    const float* __restrict__ eb1,
    const ushort* __restrict__ w2hi, const ushort* __restrict__ w2lo,
    const float* __restrict__ eb2,
    const float* __restrict__ gates, float* __restrict__ out)
{
    __shared__ __align__(16) ushort As_hi[64][40];
    __shared__ __align__(16) ushort As_lo[64][40];
    __shared__ __align__(16) ushort Ws_hi[64][40];
    __shared__ __align__(16) ushort Ws_lo[64][40];
    __shared__ __align__(16) unsigned hidb[4][32][36];   // packed hi | lo<<16

    const int e = blockIdx.y;
    const int t0 = blockIdx.x * 64;
    const int tid = threadIdx.x;
    const int lane = tid & 63;
    const int wv = tid >> 6;
    const int g  = wv & 1;
    const int hh = wv >> 1;
    const int l15 = lane & 15;
    const int l4  = lane >> 4;

    const int srow = tid >> 2;          // 0..63
    const int skoff = (tid & 3) * 8;    // 0,8,16,24

    const int tokrow = t0 + srow;
    const bool tok_ok = tokrow < BC_;
    const ushort* aghi = ahi + (size_t)tokrow * KP1 + skoff;
    const ushort* aglo = alo + (size_t)tokrow * KP1 + skoff;

    const f32x4 z4 = {0.f, 0.f, 0.f, 0.f};
    f32x4 acc2[2][6];
    #pragma unroll
    for (int m = 0; m < 2; ++m)
        #pragma unroll
        for (int n = 0; n < 6; ++n) acc2[m][n] = z4;

    const uint4 zero4 = make_uint4(0u, 0u, 0u, 0u);

    for (int ht = 0; ht < 32; ++ht) {
        const int hb = ht * 64;
        const ushort* wghi = w1hi + ((size_t)(e * H_ + hb + srow)) * KP1 + skoff;
        const ushort* wglo = w1lo + ((size_t)(e * H_ + hb + srow)) * KP1 + skoff;

        f32x4 acc1[2][2];
        #pragma unroll
        for (int m = 0; m < 2; ++m)
            #pragma unroll
            for (int n = 0; n < 2; ++n) acc1[m][n] = z4;

        for (int kt = 0; kt < 11; ++kt) {
            const int k0 = kt * 32;
            uint4 va_h = tok_ok ? *(const uint4*)(aghi + k0) : zero4;
            uint4 va_l = tok_ok ? *(const uint4*)(aglo + k0) : zero4;
            uint4 vw_h = *(const uint4*)(wghi + k0);
            uint4 vw_l = *(const uint4*)(wglo + k0);
            __syncthreads();   // previous chunk's frag reads complete
            *(uint4*)&As_hi[srow][skoff] = va_h;
            *(uint4*)&As_lo[srow][skoff] = va_l;
            *(uint4*)&Ws_hi[srow][skoff] = vw_h;
            *(uint4*)&Ws_lo[srow][skoff] = vw_l;
            __syncthreads();

            short8v a_h[2], a_l[2], b_h[2], b_l[2];
            #pragma unroll
            for (int m = 0; m < 2; ++m) {
                a_h[m] = *(const short8v*)&As_hi[g * 32 + m * 16 + l15][l4 * 8];
                a_l[m] = *(const short8v*)&As_lo[g * 32 + m * 16 + l15][l4 * 8];
            }
            #pragma unroll
            for (int n = 0; n < 2; ++n) {
                b_h[n] = *(const short8v*)&Ws_hi[hh * 32 + n * 16 + l15][l4 * 8];
                b_l[n] = *(const short8v*)&Ws_lo[hh * 32 + n * 16 + l15][l4 * 8];
            }
            #pragma unroll
            for (int m = 0; m < 2; ++m)
                #pragma unroll
                for (int n = 0; n < 2; ++n) {
                    acc1[m][n] = __builtin_amdgcn_mfma_f32_16x16x32_bf16(a_h[m], b_h[n], acc1[m][n], 0, 0, 0);
                    acc1[m][n] = __builtin_amdgcn_mfma_f32_16x16x32_bf16(a_l[m], b_h[n], acc1[m][n], 0, 0, 0);
                    acc1[m][n] = __builtin_amdgcn_mfma_f32_16x16x32_bf16(a_h[m], b_l[n], acc1[m][n], 0, 0, 0);
                }
        }

        // bias + gelu + split + pack into per-wave hid buffer
        #pragma unroll
        for (int n = 0; n < 2; ++n) {
            float bv = eb1[e * H_ + hb + hh * 32 + n * 16 + l15];
            #pragma unroll
            for (int m = 0; m < 2; ++m) {
                #pragma unroll
                for (int r = 0; r < 4; ++r) {
                    float v = gelu_f(acc1[m][n][r] + bv);
                    unsigned hbits = rne16(v);
                    float hf = __uint_as_float(hbits << 16);
                    unsigned lbits = rne16(v - hf);
                    hidb[wv][m * 16 + l4 * 4 + r][n * 16 + l15] = hbits | (lbits << 16);
                }
            }
        }

        // GEMM2 for this htile: K = 32 (wave's own h half); A from hidb (wave-local)
        short8v ah2[2], al2[2];
        #pragma unroll
        for (int m = 0; m < 2; ++m) {
            uint4 q0 = *(const uint4*)&hidb[wv][m * 16 + l15][l4 * 8];
            uint4 q1 = *(const uint4*)&hidb[wv][m * 16 + l15][l4 * 8 + 4];
            unsigned q[8] = {q0.x, q0.y, q0.z, q0.w, q1.x, q1.y, q1.z, q1.w};
            unsigned hi4[4], lo4[4];
            #pragma unroll
            for (int j = 0; j < 4; ++j) {
                hi4[j] = (q[2*j] & 0xffffu) | (q[2*j+1] << 16);
                lo4[j] = (q[2*j] >> 16)    | (q[2*j+1] & 0xffff0000u);
            }
            ah2[m] = *(short8v*)hi4;
            al2[m] = *(short8v*)lo4;
        }
        const ushort* w2bh = w2hi + ((size_t)e * P_) * H_ + hb + hh * 32 + l4 * 8;
        const ushort* w2bl = w2lo + ((size_t)e * P_) * H_ + hb + hh * 32 + l4 * 8;
        #pragma unroll
        for (int n = 0; n < 6; ++n) {
            short8v b2h = *(const short8v*)(w2bh + (size_t)(n * 16 + l15) * H_);
            short8v b2l = *(const short8v*)(w2bl + (size_t)(n * 16 + l15) * H_);
            #pragma unroll
            for (int m = 0; m < 2; ++m) {
                acc2[m][n] = __builtin_amdgcn_mfma_f32_16x16x32_bf16(ah2[m], b2h, acc2[m][n], 0, 0, 0);
                acc2[m][n] = __builtin_amdgcn_mfma_f32_16x16x32_bf16(al2[m], b2h, acc2[m][n], 0, 0, 0);
                acc2[m][n] = __builtin_amdgcn_mfma_f32_16x16x32_bf16(ah2[m], b2l, acc2[m][n], 0, 0, 0);
            }
        }
    }

    // epilogue: gate-weighted atomic accumulate (bias added once, by hh==0)
    #pragma unroll
    for (int m = 0; m < 2; ++m) {
        #pragma unroll
        for (int r = 0; r < 4; ++r) {
            int tok = t0 + g * 32 + m * 16 + l4 * 4 + r;
            if (tok < BC_) {
                float gv = gates[tok * 4 + e];
                int b = tok / C_, c = tok - (tok / C_) * C_;
                float* orow = out + (size_t)b * P_ * C_ + c;
                #pragma unroll
                for (int n = 0; n < 6; ++n) {
                    int p = n * 16 + l15;
                    float v = acc2[m][n][r];
                    if (hh == 0) v += eb2[e * P_ + p];
                    atomicAdd(orow + (size_t)p * C_, gv * v);
                }
            }
        }
    }
}

// ---------------- launch ----------------
extern "C" void kernel_launch(void* const* d_in, const int* in_sizes, int n_in,
                              void* d_out, int out_size, void* d_ws, size_t ws_size,
                              hipStream_t stream) {
    const float* x       = (const float*)d_in[0];
    const float* mdm_w   = (const float*)d_in[2];
    const float* mdm_b   = (const float*)d_in[3];
    const float* m0w1    = (const float*)d_in[4];
    const float* m0b1    = (const float*)d_in[5];
    const float* m0w2    = (const float*)d_in[6];
    const float* m0b2    = (const float*)d_in[7];
    const float* m1w1    = (const float*)d_in[8];
    const float* m1b1    = (const float*)d_in[9];
    const float* m1w2    = (const float*)d_in[10];
    const float* m1b2    = (const float*)d_in[11];
    const float* m2w1    = (const float*)d_in[12];
    const float* m2b1    = (const float*)d_in[13];
    const float* m2w2    = (const float*)d_in[14];
    const float* m2b2    = (const float*)d_in[15];
    const float* dbn_w   = (const float*)d_in[16];
    const float* dbn_b   = (const float*)d_in[17];
    const float* n1w     = (const float*)d_in[18];
    const float* n1b     = (const float*)d_in[19];
    const float* agg_w   = (const float*)d_in[20];
    const float* agg_b   = (const float*)d_in[21];
    const float* gate_w  = (const float*)d_in[22];
    const float* gate_b  = (const float*)d_in[23];
    const float* ew1     = (const float*)d_in[24];
    const float* eb1     = (const float*)d_in[25];
    const float* ew2     = (const float*)d_in[26];
    const float* eb2     = (const float*)d_in[27];
    float* out = (float*)d_out;

    float* ws   = (float*)d_ws;
    float* h    = ws;                         // BC*336 fp32 (te); later reused for ahi/alo
    float* s0   = h    + (size_t)BC_ * 336;   // BC*42
    float* s1   = s0   + (size_t)BC_ * 42;    // BC*84
    float* s2   = s1   + (size_t)BC_ * 84;    // BC*168
    float* gbuf = s2   + (size_t)BC_ * 168;   // BC*168; later w2 planes
    float* dbuf = gbuf + (size_t)BC_ * 168;   // BC*336; later w1 planes
    float* gates= dbuf + (size_t)BC_ * 336;   // BC*4

    ushort* ahi  = (ushort*)h;                        // BC*352
    ushort* alo  = ahi + (size_t)BC_ * KP1;           // BC*352 (spills into s0 region: fits)
    ushort* w2hi = (ushort*)gbuf;                     // 384*2048
    ushort* w2lo = w2hi + (size_t)E_ * P_ * H_;
    ushort* w1hi = (ushort*)dbuf;                     // 8192*352
    ushort* w1lo = w1hi + (size_t)E_ * H_ * KP1;

    const int OUTN = B_ * P_ * C_;
    k_zero<<<(OUTN + 255) / 256, 256, 0, stream>>>(out, OUTN);
    k_bnpool<<<BC_, 128, 0, stream>>>(x, mdm_w, mdm_b, h, s0, s1, s2);

    gemm_kernel<1,0><<<dim3(161,1), 256, 0, stream>>>(s0,   m0w1, m0b1, nullptr, gbuf, BC_, 42,  42);
    gemm_kernel<0,1><<<dim3(161,2), 256, 0, stream>>>(gbuf, m0w2, m0b2, s1,      s1,   BC_, 84,  42);
    gemm_kernel<1,0><<<dim3(161,2), 256, 0, stream>>>(s1,   m1w1, m1b1, nullptr, gbuf, BC_, 84,  84);
    gemm_kernel<0,1><<<dim3(161,3), 256, 0, stream>>>(gbuf, m1w2, m1b2, s2,      s2,   BC_, 168, 84);
    gemm_kernel<1,0><<<dim3(161,3), 256, 0, stream>>>(s2,   m2w1, m2b1, nullptr, gbuf, BC_, 168, 168);
    gemm_kernel<0,1><<<dim3(161,6), 256, 0, stream>>>(gbuf, m2w2, m2b2, h,       h,    BC_, 336, 168);

    k_bn2<<<(BC_ * L_ + 255) / 256, 256, 0, stream>>>(h, dbn_w, dbn_b, dbuf);
    k_gate<<<(BC_ + 255) / 256, 256, 0, stream>>>(h, gate_w, gate_b, gates);
    // gate done reading h; gemm chain done with gbuf -> safe to overwrite below
    k_ddi<<<(BC_ + 255) / 256, 256, 0, stream>>>(dbuf, n1w, n1b, agg_w, agg_b, ahi, alo);
    // ddi done reading dbuf -> convert weights into reused regions
    {
        int n1 = E_ * H_ * KP1;   // 2,883,584
        k_split<<<(n1 + 255) / 256, 256, 0, stream>>>(ew1, w1hi, w1lo, E_ * H_, L_, KP1);
        int n2 = E_ * P_ * H_;    // 786,432
        k_split<<<(n2 + 255) / 256, 256, 0, stream>>>(ew2, w2hi, w2lo, E_ * P_, H_, H_);
    }
    k_expert_mfma<<<dim3(161, E_), 256, 0, stream>>>(ahi, alo, w1hi, w1lo, eb1,
                                                     w2hi, w2lo, eb2, gates, out);
}

// Round 3
// 981.115 us; speedup vs baseline: 4.0208x; 1.0132x over previous
//
#include <hip/hip_runtime.h>
#include <math.h>

#define B_ 32
#define L_ 336
#define C_ 321
#define P_ 96
#define E_ 4
#define H_ 2048
#define BC_ (B_*C_)          // 10272
#define KP1 352              // K1 padded to multiple of 32
#define INVc 0.99999500003749969f   // 1/sqrt(1+1e-5)

typedef __attribute__((ext_vector_type(8))) short short8v;
typedef __attribute__((ext_vector_type(4))) float f32x4;

__device__ __forceinline__ float gelu_f(float x) {
    return 0.5f * x * (1.0f + erff(x * 0.70710678118654752440f));
}

__device__ __forceinline__ unsigned rne16(float v) {
    unsigned u = __float_as_uint(v);
    return (u + 0x7fffu + ((u >> 16) & 1u)) >> 16;
}

// ---------------- zero out ----------------
__global__ void k_zero(float* __restrict__ p, int n) {
    int i = blockIdx.x * blockDim.x + threadIdx.x;
    if (i < n) p[i] = 0.f;
}

// ---------------- BN1 + transpose + pyramid pooling (coalesced) ----------------
// grid (21, 32): 16 channels x 1 batch per block. x (B,L,C) read coalesced in c.
__global__ __launch_bounds__(256) void k_bnpool(
    const float* __restrict__ x, const float* __restrict__ bw, const float* __restrict__ bb,
    float* __restrict__ h, float* __restrict__ s0, float* __restrict__ s1, float* __restrict__ s2)
{
    __shared__ float t[16][337];
    __shared__ float p2[16][168];
    __shared__ float p1[16][84];
    const int b = blockIdx.y;
    const int c0 = blockIdx.x * 16;
    const int tid = threadIdx.x;

    // coalesced load + transpose into LDS
    {
        const int tl = tid >> 4, tc = tid & 15;
        const int c = c0 + tc;
        for (int l0 = 0; l0 < L_; l0 += 16) {
            int l = l0 + tl;
            float v = (c < C_) ? x[((size_t)b * L_ + l) * C_ + c] : 0.f;
            t[tc][l] = v;
        }
    }
    __syncthreads();
    // BN + write h rows (coalesced in l)
    for (int idx = tid; idx < 16 * L_; idx += 256) {
        int tt = idx / L_, l = idx - tt * L_;
        int c = c0 + tt;
        if (c < C_) {
            float v = t[tt][l] * (bw[c * L_ + l] * INVc) + bb[c * L_ + l];
            t[tt][l] = v;
            h[(size_t)(b * C_ + c) * L_ + l] = v;
        }
    }
    __syncthreads();
    for (int idx = tid; idx < 16 * 168; idx += 256) {
        int tt = idx / 168, i = idx - tt * 168;
        int c = c0 + tt;
        float v = 0.5f * (t[tt][2 * i] + t[tt][2 * i + 1]);
        p2[tt][i] = v;
        if (c < C_) s2[(size_t)(b * C_ + c) * 168 + i] = v;
    }
    __syncthreads();
    for (int idx = tid; idx < 16 * 84; idx += 256) {
        int tt = idx / 84, i = idx - tt * 84;
        int c = c0 + tt;
        float v = 0.5f * (p2[tt][2 * i] + p2[tt][2 * i + 1]);
        p1[tt][i] = v;
        if (c < C_) s1[(size_t)(b * C_ + c) * 84 + i] = v;
    }
    __syncthreads();
    for (int idx = tid; idx < 16 * 42; idx += 256) {
        int tt = idx / 42, i = idx - tt * 42;
        int c = c0 + tt;
        float v = 0.5f * (p1[tt][2 * i] + p1[tt][2 * i + 1]);
        if (c < C_) s0[(size_t)(b * C_ + c) * 42 + i] = v;
    }
}

// ---------------- generic guarded GEMM (mixer) ----------------
template<int GELU, int ADD>
__global__ __launch_bounds__(256) void gemm_kernel(
    const float* __restrict__ A, const float* __restrict__ W,
    const float* __restrict__ bias, const float* __restrict__ S,
    float* __restrict__ D, int M, int N, int K)
{
    __shared__ __align__(16) float As[16][68];
    __shared__ __align__(16) float Ws[16][68];
    int m0 = blockIdx.x * 64, n0 = blockIdx.y * 64;
    int tid = threadIdx.x;
    int tr = tid >> 4, tc = tid & 15;
    float acc[4][4];
    #pragma unroll
    for (int i = 0; i < 4; ++i)
        #pragma unroll
        for (int j = 0; j < 4; ++j) acc[i][j] = 0.f;

    int nk = (K + 15) >> 4;
    for (int kt = 0; kt < nk; ++kt) {
        int k0 = kt * 16;
        #pragma unroll
        for (int it = 0; it < 4; ++it) {
            int elem = tid + it * 256;
            int row = elem >> 4, kk = elem & 15;
            int gm = m0 + row, gk = k0 + kk;
            As[kk][row] = (gm < M && gk < K) ? A[(size_t)gm * K + gk] : 0.f;
            int gn = n0 + row;
            Ws[kk][row] = (gn < N && gk < K) ? W[(size_t)gn * K + gk] : 0.f;
        }
        __syncthreads();
        #pragma unroll
        for (int kk = 0; kk < 16; ++kk) {
            float4 a4 = *reinterpret_cast<const float4*>(&As[kk][tr * 4]);
            float4 w4 = *reinterpret_cast<const float4*>(&Ws[kk][tc * 4]);
            float av[4] = {a4.x, a4.y, a4.z, a4.w};
            float wv[4] = {w4.x, w4.y, w4.z, w4.w};
            #pragma unroll
            for (int i = 0; i < 4; ++i)
                #pragma unroll
                for (int j = 0; j < 4; ++j) acc[i][j] += av[i] * wv[j];
        }
        __syncthreads();
    }
    #pragma unroll
    for (int i = 0; i < 4; ++i) {
        int m = m0 + tr * 4 + i;
        if (m >= M) continue;
        #pragma unroll
        for (int j = 0; j < 4; ++j) {
            int n = n0 + tc * 4 + j;
            if (n >= N) continue;
            float v = acc[i][j] + bias[n];
            if (GELU) v = gelu_f(v);
            if (ADD) v += S[(size_t)m * N + n];
            D[(size_t)m * N + n] = v;
        }
    }
}

// ---------------- BN2 elementwise ----------------
__global__ void k_bn2(const float* __restrict__ te, const float* __restrict__ w,
                      const float* __restrict__ bb, float* __restrict__ d)
{
    int idx = blockIdx.x * blockDim.x + threadIdx.x;
    if (idx >= BC_ * L_) return;
    int token = idx / L_;
    int l = idx - token * L_;
    int c = token % C_;
    d[idx] = te[idx] * (w[c * L_ + l] * INVc) + bb[c * L_ + l];
}

// ---------------- DDI scan -> writes bf16 hi/lo planes (padded to 352) ----------------
__global__ __launch_bounds__(256) void k_ddi(
    const float* __restrict__ d, const float* __restrict__ n1w, const float* __restrict__ n1b,
    const float* __restrict__ aggw, const float* __restrict__ aggb,
    ushort* __restrict__ ahi, ushort* __restrict__ alo)
{
    __shared__ float sAw[144];
    __shared__ float sAb[12];
    int tid = threadIdx.x;
    if (tid < 144) sAw[tid] = aggw[tid];
    if (tid < 12) sAb[tid] = aggb[tid];
    __syncthreads();
    int token = blockIdx.x * blockDim.x + tid;
    if (token >= BC_) return;
    int c = token % C_;
    float w[12], bb[12], prev[12];
    #pragma unroll
    for (int p = 0; p < 12; ++p) { w[p] = n1w[c * 12 + p] * INVc; bb[p] = n1b[c * 12 + p]; }
    const float* drow = d + (size_t)token * L_;
    unsigned* hrow = (unsigned*)(ahi + (size_t)token * KP1);
    unsigned* lrow = (unsigned*)(alo + (size_t)token * KP1);

    auto store12 = [&](int base, const float* v) {
        #pragma unroll
        for (int j = 0; j < 6; ++j) {
            unsigned h0 = rne16(v[2*j]), h1 = rne16(v[2*j+1]);
            float f0 = __uint_as_float(h0 << 16), f1 = __uint_as_float(h1 << 16);
            unsigned l0 = rne16(v[2*j] - f0), l1 = rne16(v[2*j+1] - f1);
            hrow[(base >> 1) + j] = h0 | (h1 << 16);
            lrow[(base >> 1) + j] = l0 | (l1 << 16);
        }
    };

    #pragma unroll
    for (int p = 0; p < 12; ++p) prev[p] = drow[p];
    store12(0, prev);
    for (int t = 0; t < 27; ++t) {
        float inp[12];
        #pragma unroll
        for (int p = 0; p < 12; ++p) inp[p] = prev[p] * w[p] + bb[p];
        float o[12];
        #pragma unroll
        for (int i = 0; i < 12; ++i) {
            float a = sAb[i];
            #pragma unroll
            for (int p = 0; p < 12; ++p) a += inp[p] * sAw[i * 12 + p];
            o[i] = gelu_f(a);
        }
        const float* xp = drow + 12 + t * 12;
        #pragma unroll
        for (int p = 0; p < 12; ++p) prev[p] = o[p] + xp[p];
        store12(12 + t * 12, prev);
    }
    #pragma unroll
    for (int j = 0; j < 8; ++j) { hrow[168 + j] = 0u; lrow[168 + j] = 0u; }
}

// ---------------- gating (wave per token, coalesced) ----------------
__global__ __launch_bounds__(256) void k_gate(
    const float* __restrict__ te, const float* __restrict__ gw,
    const float* __restrict__ gb, float* __restrict__ gates)
{
    __shared__ float gw_s[4][L_];
    int tid = threadIdx.x;
    for (int idx = tid; idx < 4 * L_; idx += 256) gw_s[idx / L_][idx - (idx / L_) * L_] = gw[idx];
    __syncthreads();
    int wv = tid >> 6, lane = tid & 63;
    int token = blockIdx.x * 4 + wv;
    if (token >= BC_) return;
    const float* row = te + (size_t)token * L_;
    float a0 = 0.f, a1 = 0.f, a2 = 0.f, a3 = 0.f;
    for (int l = lane; l < L_; l += 64) {
        float tv = row[l];
        a0 += tv * gw_s[0][l]; a1 += tv * gw_s[1][l];
        a2 += tv * gw_s[2][l]; a3 += tv * gw_s[3][l];
    }
    #pragma unroll
    for (int off = 32; off > 0; off >>= 1) {
        a0 += __shfl_down(a0, off);
        a1 += __shfl_down(a1, off);
        a2 += __shfl_down(a2, off);
        a3 += __shfl_down(a3, off);
    }
    if (lane == 0) {
        float acc[4] = {a0 + gb[0], a1 + gb[1], a2 + gb[2], a3 + gb[3]};
        int im = 0;
        #pragma unroll
        for (int e = 1; e < 4; ++e) if (acc[e] > acc[im]) im = e;
        float second = -1e30f;
        #pragma unroll
        for (int e = 0; e < 4; ++e) if (e != im) second = fmaxf(second, acc[e]);
        float mx = acc[im];
        float s[4]; float ssum = 0.f;
        #pragma unroll
        for (int e = 0; e < 4; ++e) { s[e] = expf(acc[e] - mx); ssum += s[e]; }
        float dec[4]; float dmx = -1e30f;
        #pragma unroll
        for (int e = 0; e < 4; ++e) {
            s[e] /= ssum;
            dec[e] = (acc[e] < second) ? 10.f * logf(s[e] + 1.f) : 10.f * (expf(s[e]) - 1.f);
            dmx = fmaxf(dmx, dec[e]);
        }
        float g[4]; float gsum = 0.f;
        #pragma unroll
        for (int e = 0; e < 4; ++e) { g[e] = expf(dec[e] - dmx); gsum += g[e]; }
        #pragma unroll
        for (int e = 0; e < 4; ++e) gates[token * 4 + e] = g[e] / gsum;
    }
}

// ---------------- split fp32 -> bf16 hi/lo planes (K padded to Kp) ----------------
__global__ void k_split(const float* __restrict__ src, ushort* __restrict__ hi,
                        ushort* __restrict__ lo, int rows, int K, int Kp)
{
    int idx = blockIdx.x * blockDim.x + threadIdx.x;
    if (idx >= rows * Kp) return;
    int r = idx / Kp, k = idx - r * Kp;
    float v = (k < K) ? src[(size_t)r * K + k] : 0.f;
    unsigned h = rne16(v);
    float hf = __uint_as_float(h << 16);
    unsigned l = rne16(v - hf);
    hi[idx] = (ushort)h;
    lo[idx] = (ushort)l;
}

// ---------------- fused expert MLP via bf16x3 MFMA, XCD-expert affinity ----------------
// grid 648 flat. xcd = bid&7 -> expert = xcd>>1: each expert's weights stay resident in
// one XCD-pair's L2 (2.9 MB w1 + 0.8 MB w2 < 4 MB).
__global__ __launch_bounds__(256, 3) void k_expert_mfma(
    const ushort* __restrict__ ahi, const ushort* __restrict__ alo,
    const ushort* __restrict__ w1hi, const ushort* __restrict__ w1lo,
    const float* __restrict__ eb1,
    const ushort* __restrict__ w2hi, const ushort* __restrict__ w2lo,
    const float* __restrict__ eb2,
    const float* __restrict__ gates, float* __restrict__ out)
{
    __shared__ __align__(16) ushort As_hi[64][40];
    __shared__ __align__(16) ushort As_lo[64][40];
    __shared__ __align__(16) ushort Ws_hi[64][40];
    __shared__ __align__(16) ushort Ws_lo[64][40];
    __shared__ __align__(16) unsigned hidb[4][32][36];   // packed hi | lo<<16

    const int bid = blockIdx.x;
    const int e = (bid & 7) >> 1;
    const int tile = ((bid >> 3) << 1) | (bid & 1);
    if (tile >= 161) return;
    const int t0 = tile * 64;

    const int tid = threadIdx.x;
    const int lane = tid & 63;
    const int wv = tid >> 6;
    const int g  = wv & 1;
    const int hh = wv >> 1;
    const int l15 = lane & 15;
    const int l4  = lane >> 4;

    const int srow = tid >> 2;          // 0..63
    const int skoff = (tid & 3) * 8;    // 0,8,16,24

    const int tokrow = t0 + srow;
    const bool tok_ok = tokrow < BC_;
    const ushort* aghi = ahi + (size_t)tokrow * KP1 + skoff;
    const ushort* aglo = alo + (size_t)tokrow * KP1 + skoff;

    const f32x4 z4 = {0.f, 0.f, 0.f, 0.f};
    f32x4 acc2[2][6];
    #pragma unroll
    for (int m = 0; m < 2; ++m)
        #pragma unroll
        for (int n = 0; n < 6; ++n) acc2[m][n] = z4;

    const uint4 zero4 = make_uint4(0u, 0u, 0u, 0u);

    for (int ht = 0; ht < 32; ++ht) {
        const int hb = ht * 64;
        const ushort* wghi = w1hi + ((size_t)(e * H_ + hb + srow)) * KP1 + skoff;
        const ushort* wglo = w1lo + ((size_t)(e * H_ + hb + srow)) * KP1 + skoff;

        f32x4 acc1[2][2];
        #pragma unroll
        for (int m = 0; m < 2; ++m)
            #pragma unroll
            for (int n = 0; n < 2; ++n) acc1[m][n] = z4;

        for (int kt = 0; kt < 11; ++kt) {
            const int k0 = kt * 32;
            uint4 va_h = tok_ok ? *(const uint4*)(aghi + k0) : zero4;
            uint4 va_l = tok_ok ? *(const uint4*)(aglo + k0) : zero4;
            uint4 vw_h = *(const uint4*)(wghi + k0);
            uint4 vw_l = *(const uint4*)(wglo + k0);
            __syncthreads();   // previous chunk's frag reads complete
            *(uint4*)&As_hi[srow][skoff] = va_h;
            *(uint4*)&As_lo[srow][skoff] = va_l;
            *(uint4*)&Ws_hi[srow][skoff] = vw_h;
            *(uint4*)&Ws_lo[srow][skoff] = vw_l;
            __syncthreads();

            short8v a_h[2], a_l[2], b_h[2], b_l[2];
            #pragma unroll
            for (int m = 0; m < 2; ++m) {
                a_h[m] = *(const short8v*)&As_hi[g * 32 + m * 16 + l15][l4 * 8];
                a_l[m] = *(const short8v*)&As_lo[g * 32 + m * 16 + l15][l4 * 8];
            }
            #pragma unroll
            for (int n = 0; n < 2; ++n) {
                b_h[n] = *(const short8v*)&Ws_hi[hh * 32 + n * 16 + l15][l4 * 8];
                b_l[n] = *(const short8v*)&Ws_lo[hh * 32 + n * 16 + l15][l4 * 8];
            }
            #pragma unroll
            for (int m = 0; m < 2; ++m)
                #pragma unroll
                for (int n = 0; n < 2; ++n) {
                    acc1[m][n] = __builtin_amdgcn_mfma_f32_16x16x32_bf16(a_h[m], b_h[n], acc1[m][n], 0, 0, 0);
                    acc1[m][n] = __builtin_amdgcn_mfma_f32_16x16x32_bf16(a_l[m], b_h[n], acc1[m][n], 0, 0, 0);
                    acc1[m][n] = __builtin_amdgcn_mfma_f32_16x16x32_bf16(a_h[m], b_l[n], acc1[m][n], 0, 0, 0);
                }
        }

        // bias + gelu + split + pack into per-wave hid buffer
        #pragma unroll
        for (int n = 0; n < 2; ++n) {
            float bv = eb1[e * H_ + hb + hh * 32 + n * 16 + l15];
            #pragma unroll
            for (int m = 0; m < 2; ++m) {
                #pragma unroll
                for (int r = 0; r < 4; ++r) {
                    float v = gelu_f(acc1[m][n][r] + bv);
                    unsigned hbits = rne16(v);
                    float hf = __uint_as_float(hbits << 16);
                    unsigned lbits = rne16(v - hf);
                    hidb[wv][m * 16 + l4 * 4 + r][n * 16 + l15] = hbits | (lbits << 16);
                }
            }
        }

        // GEMM2 for this htile: K = 32 (wave's own h half); A from hidb (wave-local)
        short8v ah2[2], al2[2];
        #pragma unroll
        for (int m = 0; m < 2; ++m) {
            uint4 q0 = *(const uint4*)&hidb[wv][m * 16 + l15][l4 * 8];
            uint4 q1 = *(const uint4*)&hidb[wv][m * 16 + l15][l4 * 8 + 4];
            unsigned q[8] = {q0.x, q0.y, q0.z, q0.w, q1.x, q1.y, q1.z, q1.w};
            unsigned hi4[4], lo4[4];
            #pragma unroll
            for (int j = 0; j < 4; ++j) {
                hi4[j] = (q[2*j] & 0xffffu) | (q[2*j+1] << 16);
                lo4[j] = (q[2*j] >> 16)    | (q[2*j+1] & 0xffff0000u);
            }
            ah2[m] = *(short8v*)hi4;
            al2[m] = *(short8v*)lo4;
        }
        const ushort* w2bh = w2hi + ((size_t)e * P_) * H_ + hb + hh * 32 + l4 * 8;
        const ushort* w2bl = w2lo + ((size_t)e * P_) * H_ + hb + hh * 32 + l4 * 8;
        #pragma unroll
        for (int n = 0; n < 6; ++n) {
            short8v b2h = *(const short8v*)(w2bh + (size_t)(n * 16 + l15) * H_);
            short8v b2l = *(const short8v*)(w2bl + (size_t)(n * 16 + l15) * H_);
            #pragma unroll
            for (int m = 0; m < 2; ++m) {
                acc2[m][n] = __builtin_amdgcn_mfma_f32_16x16x32_bf16(ah2[m], b2h, acc2[m][n], 0, 0, 0);
                acc2[m][n] = __builtin_amdgcn_mfma_f32_16x16x32_bf16(al2[m], b2h, acc2[m][n], 0, 0, 0);
                acc2[m][n] = __builtin_amdgcn_mfma_f32_16x16x32_bf16(ah2[m], b2l, acc2[m][n], 0, 0, 0);
            }
        }
    }

    // epilogue: gate-weighted atomic accumulate (bias added once, by hh==0)
    #pragma unroll
    for (int m = 0; m < 2; ++m) {
        #pragma unroll
        for (int r = 0; r < 4; ++r) {
            int tok = t0 + g * 32 + m * 16 + l4 * 4 + r;
            if (tok < BC_) {
                float gv = gates[tok * 4 + e];
                int b = tok / C_, c = tok - (tok / C_) * C_;
                float* orow = out + (size_t)b * P_ * C_ + c;
                #pragma unroll
                for (int n = 0; n < 6; ++n) {
                    int p = n * 16 + l15;
                    float v = acc2[m][n][r];
                    if (hh == 0) v += eb2[e * P_ + p];
                    atomicAdd(orow + (size_t)p * C_, gv * v);
                }
            }
        }
    }
}

// ---------------- launch ----------------
extern "C" void kernel_launch(void* const* d_in, const int* in_sizes, int n_in,
                              void* d_out, int out_size, void* d_ws, size_t ws_size,
                              hipStream_t stream) {
    const float* x       = (const float*)d_in[0];
    const float* mdm_w   = (const float*)d_in[2];
    const float* mdm_b   = (const float*)d_in[3];
    const float* m0w1    = (const float*)d_in[4];
    const float* m0b1    = (const float*)d_in[5];
    const float* m0w2    = (const float*)d_in[6];
    const float* m0b2    = (const float*)d_in[7];
    const float* m1w1    = (const float*)d_in[8];
    const float* m1b1    = (const float*)d_in[9];
    const float* m1w2    = (const float*)d_in[10];
    const float* m1b2    = (const float*)d_in[11];
    const float* m2w1    = (const float*)d_in[12];
    const float* m2b1    = (const float*)d_in[13];
    const float* m2w2    = (const float*)d_in[14];
    const float* m2b2    = (const float*)d_in[15];
    const float* dbn_w   = (const float*)d_in[16];
    const float* dbn_b   = (const float*)d_in[17];
    const float* n1w     = (const float*)d_in[18];
    const float* n1b     = (const float*)d_in[19];
    const float* agg_w   = (const float*)d_in[20];
    const float* agg_b   = (const float*)d_in[21];
    const float* gate_w  = (const float*)d_in[22];
    const float* gate_b  = (const float*)d_in[23];
    const float* ew1     = (const float*)d_in[24];
    const float* eb1     = (const float*)d_in[25];
    const float* ew2     = (const float*)d_in[26];
    const float* eb2     = (const float*)d_in[27];
    float* out = (float*)d_out;

    float* ws   = (float*)d_ws;
    float* h    = ws;                         // BC*336 fp32 (te); later reused for ahi/alo
    float* s0   = h    + (size_t)BC_ * 336;   // BC*42
    float* s1   = s0   + (size_t)BC_ * 42;    // BC*84
    float* s2   = s1   + (size_t)BC_ * 84;    // BC*168
    float* gbuf = s2   + (size_t)BC_ * 168;   // BC*168; later w2 planes
    float* dbuf = gbuf + (size_t)BC_ * 168;   // BC*336; later w1 planes
    float* gates= dbuf + (size_t)BC_ * 336;   // BC*4

    ushort* ahi  = (ushort*)h;                        // BC*352
    ushort* alo  = ahi + (size_t)BC_ * KP1;           // BC*352 (spills into s0 region: fits)
    ushort* w2hi = (ushort*)gbuf;                     // 384*2048
    ushort* w2lo = w2hi + (size_t)E_ * P_ * H_;
    ushort* w1hi = (ushort*)dbuf;                     // 8192*352
    ushort* w1lo = w1hi + (size_t)E_ * H_ * KP1;

    const int OUTN = B_ * P_ * C_;
    k_zero<<<(OUTN + 255) / 256, 256, 0, stream>>>(out, OUTN);
    k_bnpool<<<dim3(21, 32), 256, 0, stream>>>(x, mdm_w, mdm_b, h, s0, s1, s2);

    gemm_kernel<1,0><<<dim3(161,1), 256, 0, stream>>>(s0,   m0w1, m0b1, nullptr, gbuf, BC_, 42,  42);
    gemm_kernel<0,1><<<dim3(161,2), 256, 0, stream>>>(gbuf, m0w2, m0b2, s1,      s1,   BC_, 84,  42);
    gemm_kernel<1,0><<<dim3(161,2), 256, 0, stream>>>(s1,   m1w1, m1b1, nullptr, gbuf, BC_, 84,  84);
    gemm_kernel<0,1><<<dim3(161,3), 256, 0, stream>>>(gbuf, m1w2, m1b2, s2,      s2,   BC_, 168, 84);
    gemm_kernel<1,0><<<dim3(161,3), 256, 0, stream>>>(s2,   m2w1, m2b1, nullptr, gbuf, BC_, 168, 168);
    gemm_kernel<0,1><<<dim3(161,6), 256, 0, stream>>>(gbuf, m2w2, m2b2, h,       h,    BC_, 336, 168);

    k_bn2<<<(BC_ * L_ + 255) / 256, 256, 0, stream>>>(h, dbn_w, dbn_b, dbuf);
    k_gate<<<(BC_ + 3) / 4, 256, 0, stream>>>(h, gate_w, gate_b, gates);
    // gate done reading h; gemm chain done with gbuf -> safe to overwrite below
    k_ddi<<<(BC_ + 255) / 256, 256, 0, stream>>>(dbuf, n1w, n1b, agg_w, agg_b, ahi, alo);
    // ddi done reading dbuf -> convert weights into reused regions
    {
        int n1 = E_ * H_ * KP1;   // 2,883,584
        k_split<<<(n1 + 255) / 256, 256, 0, stream>>>(ew1, w1hi, w1lo, E_ * H_, L_, KP1);
        int n2 = E_ * P_ * H_;    // 786,432
        k_split<<<(n2 + 255) / 256, 256, 0, stream>>>(ew2, w2hi, w2lo, E_ * P_, H_, H_);
    }
    k_expert_mfma<<<648, 256, 0, stream>>>(ahi, alo, w1hi, w1lo, eb1,
                                           w2hi, w2lo, eb2, gates, out);
}